// Round 1
// baseline (359.860 us; speedup 1.0000x reference)
//
#include <hip/hip_runtime.h>
#include <math.h>
#include <float.h>

// Problem constants (from reference)
#define NPT     16384
#define IN_F    34
#define SDIM    4
#define PDIM    22
#define KNN     8
#define WIDTH   126
#define NCLS    6
#define NGRAPHS 8
#define CH      8      // candidate chunks per query in kNN phase 1

// ---------------- workspace layout (bytes) ----------------
// ranges:  16 ints                      @ 0
// S    :   NPT*4  floats                @ 256
// H    :   NPT*22 floats
// PD2  :   NPT*CH*8 floats
// PIX  :   NPT*CH*8 ints
// KIDX :   NPT*8 ints
// KW   :   NPT*8 floats
// EMB  :   NPT*34 floats
// H1   :   NPT*126 floats
// H2   :   NPT*126 floats
// total ~= 29.9 MB
#define OFF_RANGES 0
#define OFF_S      256
#define OFF_H      (OFF_S    + NPT*SDIM*4)
#define OFF_PD2    (OFF_H    + NPT*PDIM*4)
#define OFF_PIX    (OFF_PD2  + NPT*CH*KNN*4)
#define OFF_KIDX   (OFF_PIX  + NPT*CH*KNN*4)
#define OFF_KW     (OFF_KIDX + NPT*KNN*4)
#define OFF_EMB    (OFF_KW   + NPT*KNN*4)
#define OFF_H1     (OFF_EMB  + NPT*IN_F*4)
#define OFF_H2     (OFF_H1   + NPT*WIDTH*4)

// ---------------------------------------------------------
// Graph ranges from sorted batch array (each present graph writes its own
// start/end exactly once; absent graphs are never read).
__global__ __launch_bounds__(256) void k_ranges(const int* __restrict__ batch,
                                                int* __restrict__ ranges) {
    int i = blockIdx.x * blockDim.x + threadIdx.x;
    if (i >= NPT) return;
    int b = batch[i];
    if (i == 0 || batch[i - 1] != b) ranges[b * 2]     = i;
    if (i == NPT - 1 || batch[i + 1] != b) ranges[b * 2 + 1] = i + 1;
}

// s = (x@Ws + bs) + 1000*batch ; h = x@Wh + bh   (conv index 1 weights)
__global__ __launch_bounds__(256) void k_sh(const float* __restrict__ x,
                                            const int* __restrict__ batch,
                                            const float* __restrict__ Ws,
                                            const float* __restrict__ bs,
                                            const float* __restrict__ Wh,
                                            const float* __restrict__ bh,
                                            float* __restrict__ S,
                                            float* __restrict__ H) {
    int i = blockIdx.x * blockDim.x + threadIdx.x;
    if (i >= NPT) return;
    float sacc[SDIM];
    float hacc[PDIM];
#pragma unroll
    for (int d = 0; d < SDIM; ++d) sacc[d] = 0.f;
#pragma unroll
    for (int p = 0; p < PDIM; ++p) hacc[p] = 0.f;
    const float* xr = x + (size_t)i * IN_F;
#pragma unroll 2
    for (int k = 0; k < IN_F; ++k) {
        float xv = xr[k];
#pragma unroll
        for (int d = 0; d < SDIM; ++d) sacc[d] += xv * Ws[k * SDIM + d];
#pragma unroll
        for (int p = 0; p < PDIM; ++p) hacc[p] += xv * Wh[k * PDIM + p];
    }
    float off = 1000.f * (float)batch[i];
#pragma unroll
    for (int d = 0; d < SDIM; ++d) S[(size_t)i * SDIM + d] = (sacc[d] + bs[d]) + off;
#pragma unroll
    for (int p = 0; p < PDIM; ++p) H[(size_t)i * PDIM + p] = hacc[p] + bh[p];
}

// kNN phase 1: thread = (query q, chunk c). Scan chunk of q's own graph,
// keep top-8 smallest d2 (strict < => ties prefer lower index, and indices
// ascend within a chunk, matching jax.lax.top_k tie-breaking).
__global__ __launch_bounds__(256) void k_knn(const float4* __restrict__ S4,
                                             const int* __restrict__ batch,
                                             const int* __restrict__ ranges,
                                             float* __restrict__ PD2,
                                             int* __restrict__ PIX) {
    int q = blockIdx.x * blockDim.x + threadIdx.x;
    if (q >= NPT) return;
    int c  = blockIdx.y;
    int b  = batch[q];
    int gs = ranges[b * 2];
    int ge = ranges[b * 2 + 1];
    int len = ge - gs;
    int j0 = gs + (int)(((long long)len * c) / CH);
    int j1 = gs + (int)(((long long)len * (c + 1)) / CH);

    float4 sq = S4[q];
    float bd[KNN];
    int   bi[KNN];
#pragma unroll
    for (int t = 0; t < KNN; ++t) { bd[t] = FLT_MAX; bi[t] = 0x7fffffff; }

    for (int j = j0; j < j1; ++j) {
        float4 sj = S4[j];
        float d0 = sq.x - sj.x;
        float d1 = sq.y - sj.y;
        float d2 = sq.z - sj.z;
        float d3 = sq.w - sj.w;
        // match reference: square each (rounded), then sequential sum, no fma
        float dd = __fadd_rn(__fadd_rn(__fadd_rn(__fmul_rn(d0, d0),
                                                 __fmul_rn(d1, d1)),
                                       __fmul_rn(d2, d2)),
                             __fmul_rn(d3, d3));
        if (dd < bd[KNN - 1]) {
            bd[KNN - 1] = dd;
            bi[KNN - 1] = j;
#pragma unroll
            for (int t = KNN - 1; t >= 1; --t) {
                if (bd[t] < bd[t - 1]) {
                    float td = bd[t]; bd[t] = bd[t - 1]; bd[t - 1] = td;
                    int   ti = bi[t]; bi[t] = bi[t - 1]; bi[t - 1] = ti;
                }
            }
        }
    }
    float* pd = PD2 + ((size_t)q * CH + c) * KNN;
    int*   pi = PIX + ((size_t)q * CH + c) * KNN;
#pragma unroll
    for (int t = 0; t < KNN; ++t) { pd[t] = bd[t]; pi[t] = bi[t]; }
}

// kNN phase 2: merge CH partial top-8 lists (lexicographic (d2, idx)),
// emit final neighbor indices + weights w = exp(-10*d2).
__global__ __launch_bounds__(256) void k_merge(const float* __restrict__ PD2,
                                               const int* __restrict__ PIX,
                                               int* __restrict__ KIDX,
                                               float* __restrict__ KW) {
    int q = blockIdx.x * blockDim.x + threadIdx.x;
    if (q >= NPT) return;
    float bd[KNN];
    int   bi[KNN];
#pragma unroll
    for (int t = 0; t < KNN; ++t) { bd[t] = FLT_MAX; bi[t] = 0x7fffffff; }
    const float* pd = PD2 + (size_t)q * CH * KNN;
    const int*   pi = PIX + (size_t)q * CH * KNN;
    for (int e = 0; e < CH * KNN; ++e) {
        float dd = pd[e];
        int   jj = pi[e];
        if (dd < bd[KNN - 1] || (dd == bd[KNN - 1] && jj < bi[KNN - 1])) {
            bd[KNN - 1] = dd;
            bi[KNN - 1] = jj;
#pragma unroll
            for (int t = KNN - 1; t >= 1; --t) {
                bool sw = (bd[t] < bd[t - 1]) ||
                          (bd[t] == bd[t - 1] && bi[t] < bi[t - 1]);
                if (sw) {
                    float td = bd[t]; bd[t] = bd[t - 1]; bd[t - 1] = td;
                    int   ti = bi[t]; bi[t] = bi[t - 1]; bi[t - 1] = ti;
                }
            }
        }
    }
#pragma unroll
    for (int t = 0; t < KNN; ++t) {
        KIDX[(size_t)q * KNN + t] = bi[t];
        KW[(size_t)q * KNN + t]   = expf(-10.f * bd[t]);
    }
}

// Gather+aggregate then emb = x@Wo1 + [mean||max]@Wo2 + bo2
__global__ __launch_bounds__(256) void k_emb(const float* __restrict__ x,
                                             const float* __restrict__ H,
                                             const int* __restrict__ KIDX,
                                             const float* __restrict__ KW,
                                             const float* __restrict__ Wo1,
                                             const float* __restrict__ Wo2,
                                             const float* __restrict__ bo2,
                                             float* __restrict__ EMB) {
    int i = blockIdx.x * blockDim.x + threadIdx.x;
    if (i >= NPT) return;
    float msum[PDIM], mmax[PDIM];
#pragma unroll
    for (int p = 0; p < PDIM; ++p) { msum[p] = 0.f; mmax[p] = -FLT_MAX; }
#pragma unroll
    for (int k = 0; k < KNN; ++k) {
        int   j = KIDX[(size_t)i * KNN + k];
        float w = KW[(size_t)i * KNN + k];
        const float* hr = H + (size_t)j * PDIM;
#pragma unroll
        for (int p = 0; p < PDIM; ++p) {
            float m = hr[p] * w;
            msum[p] += m;
            mmax[p] = fmaxf(mmax[p], m);
        }
    }
    float acc[IN_F], acc2[IN_F];
#pragma unroll
    for (int d = 0; d < IN_F; ++d) { acc[d] = 0.f; acc2[d] = 0.f; }
    const float* xr = x + (size_t)i * IN_F;
    for (int k = 0; k < IN_F; ++k) {
        float xv = xr[k];
#pragma unroll
        for (int d = 0; d < IN_F; ++d) acc[d] += xv * Wo1[k * IN_F + d];
    }
#pragma unroll
    for (int p = 0; p < PDIM; ++p) {
        float a = msum[p] * 0.125f;  // mean over K=8
        const float* wr = Wo2 + p * IN_F;
#pragma unroll 2
        for (int d = 0; d < IN_F; ++d) acc2[d] += a * wr[d];
    }
#pragma unroll
    for (int p = 0; p < PDIM; ++p) {
        float a = mmax[p];
        const float* wr = Wo2 + (PDIM + p) * IN_F;
#pragma unroll 2
        for (int d = 0; d < IN_F; ++d) acc2[d] += a * wr[d];
    }
#pragma unroll
    for (int d = 0; d < IN_F; ++d)
        EMB[(size_t)i * IN_F + d] = acc[d] + acc2[d] + bo2[d];
}

// h1 = elu(emb@W1 + b1): thread = (row, 21-wide output chunk), gridDim.y = 6
__global__ __launch_bounds__(256) void k_mlp1(const float* __restrict__ EMB,
                                              const float* __restrict__ W1,
                                              const float* __restrict__ b1,
                                              float* __restrict__ H1) {
    int i = blockIdx.x * blockDim.x + threadIdx.x;
    if (i >= NPT) return;
    int j0 = blockIdx.y * 21;
    float acc[21];
#pragma unroll
    for (int jj = 0; jj < 21; ++jj) acc[jj] = 0.f;
    for (int k = 0; k < IN_F; ++k) {
        float ev = EMB[(size_t)i * IN_F + k];
        const float* wr = W1 + k * WIDTH + j0;
#pragma unroll
        for (int jj = 0; jj < 21; ++jj) acc[jj] += ev * wr[jj];
    }
#pragma unroll
    for (int jj = 0; jj < 21; ++jj) {
        float v = acc[jj] + b1[j0 + jj];
        H1[(size_t)i * WIDTH + j0 + jj] = v > 0.f ? v : expm1f(v);
    }
}

// h2 = elu(h1@W2 + b2)
__global__ __launch_bounds__(256) void k_mlp2(const float* __restrict__ H1,
                                              const float* __restrict__ W2,
                                              const float* __restrict__ b2,
                                              float* __restrict__ H2) {
    int i = blockIdx.x * blockDim.x + threadIdx.x;
    if (i >= NPT) return;
    int j0 = blockIdx.y * 21;
    float acc[21];
#pragma unroll
    for (int jj = 0; jj < 21; ++jj) acc[jj] = 0.f;
    for (int k = 0; k < WIDTH; ++k) {
        float hv = H1[(size_t)i * WIDTH + k];
        const float* wr = W2 + k * WIDTH + j0;
#pragma unroll
        for (int jj = 0; jj < 21; ++jj) acc[jj] += hv * wr[jj];
    }
#pragma unroll
    for (int jj = 0; jj < 21; ++jj) {
        float v = acc[jj] + b2[j0 + jj];
        H2[(size_t)i * WIDTH + j0 + jj] = v > 0.f ? v : expm1f(v);
    }
}

// out = h2@W3 + b3
__global__ __launch_bounds__(256) void k_out(const float* __restrict__ H2,
                                             const float* __restrict__ W3,
                                             const float* __restrict__ b3,
                                             float* __restrict__ out) {
    int i = blockIdx.x * blockDim.x + threadIdx.x;
    if (i >= NPT) return;
    float acc[NCLS];
#pragma unroll
    for (int cc = 0; cc < NCLS; ++cc) acc[cc] = 0.f;
    for (int k = 0; k < WIDTH; ++k) {
        float hv = H2[(size_t)i * WIDTH + k];
        const float* wr = W3 + k * NCLS;
#pragma unroll
        for (int cc = 0; cc < NCLS; ++cc) acc[cc] += hv * wr[cc];
    }
#pragma unroll
    for (int cc = 0; cc < NCLS; ++cc)
        out[(size_t)i * NCLS + cc] = acc[cc] + b3[cc];
}

extern "C" void kernel_launch(void* const* d_in, const int* in_sizes, int n_in,
                              void* d_out, int out_size, void* d_ws, size_t ws_size,
                              hipStream_t stream) {
    const float* x     = (const float*)d_in[0];
    const int*   batch = (const int*)d_in[1];
    // Only conv index NCONV-1 == 1 affects the output (loop discards earlier)
    const float* Ws  = (const float*)d_in[2] + IN_F * SDIM;        // [34,4]
    const float* bs  = (const float*)d_in[3] + SDIM;               // [4]
    const float* Wh  = (const float*)d_in[4] + IN_F * PDIM;        // [34,22]
    const float* bh  = (const float*)d_in[5] + PDIM;               // [22]
    const float* Wo1 = (const float*)d_in[6] + IN_F * IN_F;        // [34,34]
    const float* Wo2 = (const float*)d_in[7] + 2 * PDIM * IN_F;    // [44,34]
    const float* bo2 = (const float*)d_in[8] + IN_F;               // [34]
    const float* W1  = (const float*)d_in[9];
    const float* b1  = (const float*)d_in[10];
    const float* W2  = (const float*)d_in[11];
    const float* b2  = (const float*)d_in[12];
    const float* W3  = (const float*)d_in[13];
    const float* b3  = (const float*)d_in[14];
    float* out = (float*)d_out;

    char* ws = (char*)d_ws;
    int*   ranges = (int*)(ws + OFF_RANGES);
    float* S      = (float*)(ws + OFF_S);
    float* H      = (float*)(ws + OFF_H);
    float* PD2    = (float*)(ws + OFF_PD2);
    int*   PIX    = (int*)(ws + OFF_PIX);
    int*   KIDX   = (int*)(ws + OFF_KIDX);
    float* KW     = (float*)(ws + OFF_KW);
    float* EMB    = (float*)(ws + OFF_EMB);
    float* H1     = (float*)(ws + OFF_H1);
    float* H2     = (float*)(ws + OFF_H2);

    dim3 blk(256);
    dim3 g64(NPT / 256);

    k_ranges<<<g64, blk, 0, stream>>>(batch, ranges);
    k_sh<<<g64, blk, 0, stream>>>(x, batch, Ws, bs, Wh, bh, S, H);
    k_knn<<<dim3(NPT / 256, CH), blk, 0, stream>>>((const float4*)S, batch, ranges, PD2, PIX);
    k_merge<<<g64, blk, 0, stream>>>(PD2, PIX, KIDX, KW);
    k_emb<<<g64, blk, 0, stream>>>(x, H, KIDX, KW, Wo1, Wo2, bo2, EMB);
    k_mlp1<<<dim3(NPT / 256, WIDTH / 21), blk, 0, stream>>>(EMB, W1, b1, H1);
    k_mlp2<<<dim3(NPT / 256, WIDTH / 21), blk, 0, stream>>>(H1, W2, b2, H2);
    k_out<<<g64, blk, 0, stream>>>(H2, W3, b3, out);
}

// Round 2
// 289.268 us; speedup vs baseline: 1.2440x; 1.2440x over previous
//
#include <hip/hip_runtime.h>
#include <math.h>
#include <float.h>

// Problem constants (from reference)
#define NPT     16384
#define IN_F    34
#define SDIM    4
#define PDIM    22
#define KNN     8
#define WIDTH   126
#define NCLS    6
#define CH      8      // candidate chunks per query in kNN phase 1
#define ROWS    32     // rows per fused-MLP block

// ---------------- workspace layout (bytes) ----------------
#define OFF_RANGES 0
#define OFF_S      256
#define OFF_H      (OFF_S    + NPT*SDIM*4)
#define OFF_PD2    (OFF_H    + NPT*PDIM*4)
#define OFF_PIX    (OFF_PD2  + NPT*CH*KNN*4)
#define OFF_KIDX   (OFF_PIX  + NPT*CH*KNN*4)
#define OFF_KW     (OFF_KIDX + NPT*KNN*4)
// total ~= 11.2 MB

// ---------------------------------------------------------
// Graph ranges from sorted batch array.
__global__ __launch_bounds__(256) void k_ranges(const int* __restrict__ batch,
                                                int* __restrict__ ranges) {
    int i = blockIdx.x * blockDim.x + threadIdx.x;
    if (i >= NPT) return;
    int b = batch[i];
    if (i == 0 || batch[i - 1] != b) ranges[b * 2]     = i;
    if (i == NPT - 1 || batch[i + 1] != b) ranges[b * 2 + 1] = i + 1;
}

// s = (x@Ws + bs) + 1000*batch ; h = x@Wh + bh   (conv index 1 weights)
// Output-parallel: thread = (row i, output slot o in 0..31); o<4 -> S, 4..25 -> H.
__global__ __launch_bounds__(256) void k_sh(const float* __restrict__ x,
                                            const int* __restrict__ batch,
                                            const float* __restrict__ Ws,
                                            const float* __restrict__ bs,
                                            const float* __restrict__ Wh,
                                            const float* __restrict__ bh,
                                            float* __restrict__ S,
                                            float* __restrict__ H) {
    int t = blockIdx.x * blockDim.x + threadIdx.x;
    int i = t >> 5;
    int o = t & 31;
    if (i >= NPT) return;
    const float* xr = x + (size_t)i * IN_F;
    if (o < SDIM) {
        float acc = 0.f;
        for (int k = 0; k < IN_F; ++k) acc += xr[k] * Ws[k * SDIM + o];
        S[(size_t)i * SDIM + o] = (acc + bs[o]) + 1000.f * (float)batch[i];
    } else if (o < SDIM + PDIM) {
        int p = o - SDIM;
        float acc = 0.f;
        for (int k = 0; k < IN_F; ++k) acc += xr[k] * Wh[k * PDIM + p];
        H[(size_t)i * PDIM + p] = acc + bh[p];
    }
}

// kNN phase 1: thread = (query q, chunk c). Strict-< insertion matches
// jax.lax.top_k tie-breaking (lower index wins; indices ascend in-chunk).
__global__ __launch_bounds__(256) void k_knn(const float4* __restrict__ S4,
                                             const int* __restrict__ batch,
                                             const int* __restrict__ ranges,
                                             float* __restrict__ PD2,
                                             int* __restrict__ PIX) {
    int q = blockIdx.x * blockDim.x + threadIdx.x;
    if (q >= NPT) return;
    int c  = blockIdx.y;
    int b  = batch[q];
    int gs = ranges[b * 2];
    int ge = ranges[b * 2 + 1];
    int len = ge - gs;
    int j0 = gs + (int)(((long long)len * c) / CH);
    int j1 = gs + (int)(((long long)len * (c + 1)) / CH);

    float4 sq = S4[q];
    float bd[KNN];
    int   bi[KNN];
#pragma unroll
    for (int t = 0; t < KNN; ++t) { bd[t] = FLT_MAX; bi[t] = 0x7fffffff; }

    for (int j = j0; j < j1; ++j) {
        float4 sj = S4[j];
        float d0 = sq.x - sj.x;
        float d1 = sq.y - sj.y;
        float d2 = sq.z - sj.z;
        float d3 = sq.w - sj.w;
        float dd = __fadd_rn(__fadd_rn(__fadd_rn(__fmul_rn(d0, d0),
                                                 __fmul_rn(d1, d1)),
                                       __fmul_rn(d2, d2)),
                             __fmul_rn(d3, d3));
        if (dd < bd[KNN - 1]) {
            bd[KNN - 1] = dd;
            bi[KNN - 1] = j;
#pragma unroll
            for (int t = KNN - 1; t >= 1; --t) {
                if (bd[t] < bd[t - 1]) {
                    float td = bd[t]; bd[t] = bd[t - 1]; bd[t - 1] = td;
                    int   ti = bi[t]; bi[t] = bi[t - 1]; bi[t - 1] = ti;
                }
            }
        }
    }
    float* pd = PD2 + ((size_t)q * CH + c) * KNN;
    int*   pi = PIX + ((size_t)q * CH + c) * KNN;
#pragma unroll
    for (int t = 0; t < KNN; ++t) { pd[t] = bd[t]; pi[t] = bi[t]; }
}

// kNN phase 2: merge CH partial top-8 lists (lexicographic (d2, idx)).
__global__ __launch_bounds__(64) void k_merge(const float* __restrict__ PD2,
                                              const int* __restrict__ PIX,
                                              int* __restrict__ KIDX,
                                              float* __restrict__ KW) {
    int q = blockIdx.x * blockDim.x + threadIdx.x;
    if (q >= NPT) return;
    float bd[KNN];
    int   bi[KNN];
#pragma unroll
    for (int t = 0; t < KNN; ++t) { bd[t] = FLT_MAX; bi[t] = 0x7fffffff; }
    const float* pd = PD2 + (size_t)q * CH * KNN;
    const int*   pi = PIX + (size_t)q * CH * KNN;
    for (int e = 0; e < CH * KNN; ++e) {
        float dd = pd[e];
        int   jj = pi[e];
        if (dd < bd[KNN - 1] || (dd == bd[KNN - 1] && jj < bi[KNN - 1])) {
            bd[KNN - 1] = dd;
            bi[KNN - 1] = jj;
#pragma unroll
            for (int t = KNN - 1; t >= 1; --t) {
                bool sw = (bd[t] < bd[t - 1]) ||
                          (bd[t] == bd[t - 1] && bi[t] < bi[t - 1]);
                if (sw) {
                    float td = bd[t]; bd[t] = bd[t - 1]; bd[t - 1] = td;
                    int   ti = bi[t]; bi[t] = bi[t - 1]; bi[t - 1] = ti;
                }
            }
        }
    }
#pragma unroll
    for (int t = 0; t < KNN; ++t) {
        KIDX[(size_t)q * KNN + t] = bi[t];
        KW[(size_t)q * KNN + t]   = expf(-10.f * bd[t]);
    }
}

// Fused: gather/aggregate -> emb = x@Wo1 + agg@Wo2 + bo2 -> MLP(3 layers) -> out
// Block: 256 threads = 32 rows x 8 out-chunks; all activations staged in LDS.
__global__ __launch_bounds__(256) void k_fused(const float* __restrict__ x,
                                               const float* __restrict__ H,
                                               const int* __restrict__ KIDX,
                                               const float* __restrict__ KW,
                                               const float* __restrict__ Wo1,
                                               const float* __restrict__ Wo2,
                                               const float* __restrict__ bo2,
                                               const float* __restrict__ W1,
                                               const float* __restrict__ b1,
                                               const float* __restrict__ W2,
                                               const float* __restrict__ b2,
                                               const float* __restrict__ W3,
                                               const float* __restrict__ b3,
                                               float* __restrict__ out) {
    __shared__ float xt[ROWS * IN_F];         // 32x34
    __shared__ float aggt[ROWS * 2 * PDIM];   // 32x44 : [mean(22) | max(22)]
    __shared__ float et[ROWS * IN_F];         // 32x34
    __shared__ float h1t[ROWS * WIDTH];       // 32x126
    __shared__ float h2t[ROWS * WIDTH];       // 32x126

    const int tid  = threadIdx.x;
    const int row0 = blockIdx.x * ROWS;
    const int r    = tid >> 3;     // 0..31
    const int c    = tid & 7;      // 0..7
    const int gi   = row0 + r;

    // stage x tile (coalesced)
    for (int t = tid; t < ROWS * IN_F; t += 256)
        xt[t] = x[(size_t)row0 * IN_F + t];

    // gather + aggregate: lane c handles dims {c, c+8, c+16(<22)}
    {
        const int p0 = c, p1 = c + 8, p2 = c + 16;
        const bool has2 = (p2 < PDIM);
        float s0 = 0.f, s1 = 0.f, s2 = 0.f;
        float m0 = -FLT_MAX, m1 = -FLT_MAX, m2 = -FLT_MAX;
#pragma unroll
        for (int k = 0; k < KNN; ++k) {
            int   j = KIDX[(size_t)gi * KNN + k];
            float w = KW[(size_t)gi * KNN + k];
            const float* hr = H + (size_t)j * PDIM;
            float v0 = hr[p0] * w; s0 += v0; m0 = fmaxf(m0, v0);
            float v1 = hr[p1] * w; s1 += v1; m1 = fmaxf(m1, v1);
            if (has2) { float v2 = hr[p2] * w; s2 += v2; m2 = fmaxf(m2, v2); }
        }
        aggt[r * 44 + p0] = s0 * 0.125f; aggt[r * 44 + PDIM + p0] = m0;
        aggt[r * 44 + p1] = s1 * 0.125f; aggt[r * 44 + PDIM + p1] = m1;
        if (has2) { aggt[r * 44 + p2] = s2 * 0.125f; aggt[r * 44 + PDIM + p2] = m2; }
    }
    __syncthreads();

    // et = x@Wo1 + agg@Wo2 + bo2 ; chunks of 5 (j0 = min(5c,29), overlap lanes
    // compute bitwise-identical duplicates -> benign same-value LDS writes)
    {
        const int j0 = (5 * c < 29) ? 5 * c : 29;
        float acc[5];
#pragma unroll
        for (int jj = 0; jj < 5; ++jj) acc[jj] = 0.f;
        const float* ar = xt + r * IN_F;
        for (int k = 0; k < IN_F; ++k) {
            float av = ar[k];
            const float* wr = Wo1 + k * IN_F + j0;
#pragma unroll
            for (int jj = 0; jj < 5; ++jj) acc[jj] += av * wr[jj];
        }
        float acc2[5];
#pragma unroll
        for (int jj = 0; jj < 5; ++jj) acc2[jj] = 0.f;
        const float* gr = aggt + r * 44;
        for (int p = 0; p < 2 * PDIM; ++p) {
            float av = gr[p];
            const float* wr = Wo2 + p * IN_F + j0;
#pragma unroll
            for (int jj = 0; jj < 5; ++jj) acc2[jj] += av * wr[jj];
        }
#pragma unroll
        for (int jj = 0; jj < 5; ++jj)
            et[r * IN_F + j0 + jj] = acc[jj] + acc2[jj] + bo2[j0 + jj];
    }
    __syncthreads();

    // h1 = elu(et@W1 + b1) ; chunks of 16 (j0 = min(16c,110))
    {
        const int j0 = (16 * c < 110) ? 16 * c : 110;
        float acc[16];
#pragma unroll
        for (int jj = 0; jj < 16; ++jj) acc[jj] = 0.f;
        const float* ar = et + r * IN_F;
        for (int k = 0; k < IN_F; ++k) {
            float av = ar[k];
            const float* wr = W1 + k * WIDTH + j0;
#pragma unroll
            for (int jj = 0; jj < 16; ++jj) acc[jj] += av * wr[jj];
        }
#pragma unroll
        for (int jj = 0; jj < 16; ++jj) {
            float v = acc[jj] + b1[j0 + jj];
            h1t[r * WIDTH + j0 + jj] = v > 0.f ? v : expm1f(v);
        }
    }
    __syncthreads();

    // h2 = elu(h1@W2 + b2)
    {
        const int j0 = (16 * c < 110) ? 16 * c : 110;
        float acc[16];
#pragma unroll
        for (int jj = 0; jj < 16; ++jj) acc[jj] = 0.f;
        const float* ar = h1t + r * WIDTH;
        for (int k = 0; k < WIDTH; ++k) {
            float av = ar[k];
            const float* wr = W2 + k * WIDTH + j0;
#pragma unroll
            for (int jj = 0; jj < 16; ++jj) acc[jj] += av * wr[jj];
        }
#pragma unroll
        for (int jj = 0; jj < 16; ++jj) {
            float v = acc[jj] + b2[j0 + jj];
            h2t[r * WIDTH + j0 + jj] = v > 0.f ? v : expm1f(v);
        }
    }
    __syncthreads();

    // out = h2@W3 + b3 ; lane c<6 computes one class
    if (c < NCLS) {
        float acc = 0.f;
        const float* ar = h2t + r * WIDTH;
        for (int k = 0; k < WIDTH; ++k) acc += ar[k] * W3[k * NCLS + c];
        out[(size_t)gi * NCLS + c] = acc + b3[c];
    }
}

extern "C" void kernel_launch(void* const* d_in, const int* in_sizes, int n_in,
                              void* d_out, int out_size, void* d_ws, size_t ws_size,
                              hipStream_t stream) {
    const float* x     = (const float*)d_in[0];
    const int*   batch = (const int*)d_in[1];
    // Only conv index NCONV-1 == 1 affects the output (loop discards earlier)
    const float* Ws  = (const float*)d_in[2] + IN_F * SDIM;
    const float* bs  = (const float*)d_in[3] + SDIM;
    const float* Wh  = (const float*)d_in[4] + IN_F * PDIM;
    const float* bh  = (const float*)d_in[5] + PDIM;
    const float* Wo1 = (const float*)d_in[6] + IN_F * IN_F;
    const float* Wo2 = (const float*)d_in[7] + 2 * PDIM * IN_F;
    const float* bo2 = (const float*)d_in[8] + IN_F;
    const float* W1  = (const float*)d_in[9];
    const float* b1  = (const float*)d_in[10];
    const float* W2  = (const float*)d_in[11];
    const float* b2  = (const float*)d_in[12];
    const float* W3  = (const float*)d_in[13];
    const float* b3  = (const float*)d_in[14];
    float* out = (float*)d_out;

    char* ws = (char*)d_ws;
    int*   ranges = (int*)(ws + OFF_RANGES);
    float* S      = (float*)(ws + OFF_S);
    float* H      = (float*)(ws + OFF_H);
    float* PD2    = (float*)(ws + OFF_PD2);
    int*   PIX    = (int*)(ws + OFF_PIX);
    int*   KIDX   = (int*)(ws + OFF_KIDX);
    float* KW     = (float*)(ws + OFF_KW);

    k_ranges<<<dim3(NPT / 256), dim3(256), 0, stream>>>(batch, ranges);
    k_sh<<<dim3(NPT * 32 / 256), dim3(256), 0, stream>>>(x, batch, Ws, bs, Wh, bh, S, H);
    k_knn<<<dim3(NPT / 256, CH), dim3(256), 0, stream>>>((const float4*)S, batch, ranges, PD2, PIX);
    k_merge<<<dim3(NPT / 64), dim3(64), 0, stream>>>(PD2, PIX, KIDX, KW);
    k_fused<<<dim3(NPT / ROWS), dim3(256), 0, stream>>>(x, H, KIDX, KW, Wo1, Wo2, bo2,
                                                        W1, b1, W2, b2, W3, b3, out);
}

// Round 3
// 219.097 us; speedup vs baseline: 1.6425x; 1.3203x over previous
//
#include <hip/hip_runtime.h>
#include <math.h>
#include <float.h>

// Problem constants (from reference)
#define NPT     16384
#define IN_F    34
#define SDIM    4
#define PDIM    22
#define KNN     8
#define WIDTH   126
#define NCLS    6
#define CH      16     // candidate chunks per query in kNN phase 1
#define ROWS    16     // rows per fused-MLP block

// ---------------- workspace layout (bytes), total ~19.5 MB ----------------
#define OFF_RANGES 0
#define OFF_S      256
#define OFF_H      (OFF_S    + NPT*SDIM*4)
#define OFF_PD2    (OFF_H    + NPT*PDIM*4)
#define OFF_PIX    (OFF_PD2  + NPT*CH*KNN*4)
#define OFF_KIDX   (OFF_PIX  + NPT*CH*KNN*4)
#define OFF_KW     (OFF_KIDX + NPT*KNN*4)

// ---------------------------------------------------------
__global__ __launch_bounds__(256) void k_ranges(const int* __restrict__ batch,
                                                int* __restrict__ ranges) {
    int i = blockIdx.x * blockDim.x + threadIdx.x;
    if (i >= NPT) return;
    int b = batch[i];
    if (i == 0 || batch[i - 1] != b) ranges[b * 2]     = i;
    if (i == NPT - 1 || batch[i + 1] != b) ranges[b * 2 + 1] = i + 1;
}

// s = (x@Ws + bs) + 1000*batch ; h = x@Wh + bh   (conv index 1 weights)
__global__ __launch_bounds__(256) void k_sh(const float* __restrict__ x,
                                            const int* __restrict__ batch,
                                            const float* __restrict__ Ws,
                                            const float* __restrict__ bs,
                                            const float* __restrict__ Wh,
                                            const float* __restrict__ bh,
                                            float* __restrict__ S,
                                            float* __restrict__ H) {
    int t = blockIdx.x * blockDim.x + threadIdx.x;
    int i = t >> 5;
    int o = t & 31;
    if (i >= NPT) return;
    const float* xr = x + (size_t)i * IN_F;
    if (o < SDIM) {
        float acc = 0.f;
        for (int k = 0; k < IN_F; ++k) acc += xr[k] * Ws[k * SDIM + o];
        S[(size_t)i * SDIM + o] = (acc + bs[o]) + 1000.f * (float)batch[i];
    } else if (o < SDIM + PDIM) {
        int p = o - SDIM;
        float acc = 0.f;
        for (int k = 0; k < IN_F; ++k) acc += xr[k] * Wh[k * PDIM + p];
        H[(size_t)i * PDIM + p] = acc + bh[p];
    }
}

// kNN phase 1: thread = (query q, chunk c). Strict-< insertion matches
// jax.lax.top_k tie-breaking (lower index wins; indices ascend in-chunk).
__global__ __launch_bounds__(256) void k_knn(const float4* __restrict__ S4,
                                             const int* __restrict__ batch,
                                             const int* __restrict__ ranges,
                                             float* __restrict__ PD2,
                                             int* __restrict__ PIX) {
    int q = blockIdx.x * blockDim.x + threadIdx.x;
    if (q >= NPT) return;
    int c  = blockIdx.y;
    int b  = batch[q];
    int gs = ranges[b * 2];
    int ge = ranges[b * 2 + 1];
    int len = ge - gs;
    int j0 = gs + (int)(((long long)len * c) / CH);
    int j1 = gs + (int)(((long long)len * (c + 1)) / CH);

    float4 sq = S4[q];
    float bd[KNN];
    int   bi[KNN];
#pragma unroll
    for (int t = 0; t < KNN; ++t) { bd[t] = FLT_MAX; bi[t] = 0x7fffffff; }

    for (int j = j0; j < j1; ++j) {
        float4 sj = S4[j];
        float d0 = sq.x - sj.x;
        float d1 = sq.y - sj.y;
        float d2 = sq.z - sj.z;
        float d3 = sq.w - sj.w;
        float dd = __fadd_rn(__fadd_rn(__fadd_rn(__fmul_rn(d0, d0),
                                                 __fmul_rn(d1, d1)),
                                       __fmul_rn(d2, d2)),
                             __fmul_rn(d3, d3));
        if (dd < bd[KNN - 1]) {
            bd[KNN - 1] = dd;
            bi[KNN - 1] = j;
#pragma unroll
            for (int t = KNN - 1; t >= 1; --t) {
                if (bd[t] < bd[t - 1]) {
                    float td = bd[t]; bd[t] = bd[t - 1]; bd[t - 1] = td;
                    int   ti = bi[t]; bi[t] = bi[t - 1]; bi[t - 1] = ti;
                }
            }
        }
    }
    float* pd = PD2 + ((size_t)q * CH + c) * KNN;
    int*   pi = PIX + ((size_t)q * CH + c) * KNN;
#pragma unroll
    for (int t = 0; t < KNN; ++t) { pd[t] = bd[t]; pi[t] = bi[t]; }
}

// kNN phase 2: merge CH partial top-8 lists (lexicographic (d2, idx)).
__global__ __launch_bounds__(64) void k_merge(const float* __restrict__ PD2,
                                              const int* __restrict__ PIX,
                                              int* __restrict__ KIDX,
                                              float* __restrict__ KW) {
    int q = blockIdx.x * blockDim.x + threadIdx.x;
    if (q >= NPT) return;
    float bd[KNN];
    int   bi[KNN];
#pragma unroll
    for (int t = 0; t < KNN; ++t) { bd[t] = FLT_MAX; bi[t] = 0x7fffffff; }
    const float* pd = PD2 + (size_t)q * CH * KNN;
    const int*   pi = PIX + (size_t)q * CH * KNN;
    for (int e = 0; e < CH * KNN; ++e) {
        float dd = pd[e];
        int   jj = pi[e];
        if (dd < bd[KNN - 1] || (dd == bd[KNN - 1] && jj < bi[KNN - 1])) {
            bd[KNN - 1] = dd;
            bi[KNN - 1] = jj;
#pragma unroll
            for (int t = KNN - 1; t >= 1; --t) {
                bool sw = (bd[t] < bd[t - 1]) ||
                          (bd[t] == bd[t - 1] && bi[t] < bi[t - 1]);
                if (sw) {
                    float td = bd[t]; bd[t] = bd[t - 1]; bd[t - 1] = td;
                    int   ti = bi[t]; bi[t] = bi[t - 1]; bi[t - 1] = ti;
                }
            }
        }
    }
#pragma unroll
    for (int t = 0; t < KNN; ++t) {
        KIDX[(size_t)q * KNN + t] = bi[t];
        KW[(size_t)q * KNN + t]   = expf(-10.f * bd[t]);
    }
}

// Fused: gather/aggregate -> emb -> MLP(3 layers) -> out
// Block: 256 threads = 16 rows x 16 out-chunks; activations staged in LDS.
// acc arrays kept <=8 wide and k-loops unroll-bounded to avoid VGPR spills
// (round-2 version hit the 256-VGPR cap and wrote 24 MB of scratch).
__global__ __launch_bounds__(256) void k_fused(const float* __restrict__ x,
                                               const float* __restrict__ H,
                                               const int* __restrict__ KIDX,
                                               const float* __restrict__ KW,
                                               const float* __restrict__ Wo1,
                                               const float* __restrict__ Wo2,
                                               const float* __restrict__ bo2,
                                               const float* __restrict__ W1,
                                               const float* __restrict__ b1,
                                               const float* __restrict__ W2,
                                               const float* __restrict__ b2,
                                               const float* __restrict__ W3,
                                               const float* __restrict__ b3,
                                               float* __restrict__ out) {
    __shared__ float xt[ROWS * IN_F];          // 16x34
    __shared__ float aggt[ROWS * 2 * PDIM];    // 16x44 : [mean(22) | max(22)]
    __shared__ float et[ROWS * IN_F];          // 16x34
    __shared__ float h1t[ROWS * WIDTH];        // 16x126
    __shared__ float h2t[ROWS * WIDTH];        // 16x126  (total 23.3 KB)

    const int tid  = threadIdx.x;
    const int row0 = blockIdx.x * ROWS;
    const int r    = tid >> 4;     // 0..15
    const int c    = tid & 15;     // 0..15
    const int gi   = row0 + r;

    // stage x tile (coalesced)
    for (int t = tid; t < ROWS * IN_F; t += 256)
        xt[t] = x[(size_t)row0 * IN_F + t];

    // gather + aggregate: lane c<11 handles dims {c, c+11}
    if (c < 11) {
        const int p0 = c, p1 = c + 11;
        float s0 = 0.f, s1 = 0.f;
        float m0 = -FLT_MAX, m1 = -FLT_MAX;
#pragma unroll
        for (int k = 0; k < KNN; ++k) {
            int   j = KIDX[(size_t)gi * KNN + k];
            float w = KW[(size_t)gi * KNN + k];
            const float* hr = H + (size_t)j * PDIM;
            float v0 = hr[p0] * w; s0 += v0; m0 = fmaxf(m0, v0);
            float v1 = hr[p1] * w; s1 += v1; m1 = fmaxf(m1, v1);
        }
        aggt[r * 44 + p0] = s0 * 0.125f; aggt[r * 44 + PDIM + p0] = m0;
        aggt[r * 44 + p1] = s1 * 0.125f; aggt[r * 44 + PDIM + p1] = m1;
    }
    __syncthreads();

    // et = x@Wo1 + agg@Wo2 + bo2 ; 3-wide chunks, j0=min(3c,31); overlap
    // lanes write bitwise-identical duplicates (benign)
    {
        const int j0 = (3 * c < 31) ? 3 * c : 31;
        float acc[3] = {0.f, 0.f, 0.f};
        const float* ar = xt + r * IN_F;
#pragma unroll 4
        for (int k = 0; k < IN_F; ++k) {
            float av = ar[k];
            const float* wr = Wo1 + k * IN_F + j0;
#pragma unroll
            for (int jj = 0; jj < 3; ++jj) acc[jj] += av * wr[jj];
        }
        const float* gr = aggt + r * 44;
#pragma unroll 4
        for (int p = 0; p < 2 * PDIM; ++p) {
            float av = gr[p];
            const float* wr = Wo2 + p * IN_F + j0;
#pragma unroll
            for (int jj = 0; jj < 3; ++jj) acc[jj] += av * wr[jj];
        }
#pragma unroll
        for (int jj = 0; jj < 3; ++jj)
            et[r * IN_F + j0 + jj] = acc[jj] + bo2[j0 + jj];
    }
    __syncthreads();

    // h1 = elu(et@W1 + b1) ; 8-wide chunks, j0=min(8c,118)
    {
        const int j0 = (8 * c < 118) ? 8 * c : 118;
        float acc[8] = {0.f, 0.f, 0.f, 0.f, 0.f, 0.f, 0.f, 0.f};
        const float* ar = et + r * IN_F;
#pragma unroll 4
        for (int k = 0; k < IN_F; ++k) {
            float av = ar[k];
            const float* wr = W1 + k * WIDTH + j0;
#pragma unroll
            for (int jj = 0; jj < 8; ++jj) acc[jj] += av * wr[jj];
        }
#pragma unroll
        for (int jj = 0; jj < 8; ++jj) {
            float v = acc[jj] + b1[j0 + jj];
            h1t[r * WIDTH + j0 + jj] = v > 0.f ? v : expm1f(v);
        }
    }
    __syncthreads();

    // h2 = elu(h1@W2 + b2)
    {
        const int j0 = (8 * c < 118) ? 8 * c : 118;
        float acc[8] = {0.f, 0.f, 0.f, 0.f, 0.f, 0.f, 0.f, 0.f};
        const float* ar = h1t + r * WIDTH;
#pragma unroll 4
        for (int k = 0; k < WIDTH; ++k) {
            float av = ar[k];
            const float* wr = W2 + k * WIDTH + j0;
#pragma unroll
            for (int jj = 0; jj < 8; ++jj) acc[jj] += av * wr[jj];
        }
#pragma unroll
        for (int jj = 0; jj < 8; ++jj) {
            float v = acc[jj] + b2[j0 + jj];
            h2t[r * WIDTH + j0 + jj] = v > 0.f ? v : expm1f(v);
        }
    }
    __syncthreads();

    // out = h2@W3 + b3 ; lane c<6 computes one class
    if (c < NCLS) {
        float acc = 0.f;
        const float* ar = h2t + r * WIDTH;
#pragma unroll 4
        for (int k = 0; k < WIDTH; ++k) acc += ar[k] * W3[k * NCLS + c];
        out[(size_t)gi * NCLS + c] = acc + b3[c];
    }
}

extern "C" void kernel_launch(void* const* d_in, const int* in_sizes, int n_in,
                              void* d_out, int out_size, void* d_ws, size_t ws_size,
                              hipStream_t stream) {
    const float* x     = (const float*)d_in[0];
    const int*   batch = (const int*)d_in[1];
    // Only conv index NCONV-1 == 1 affects the output (loop discards earlier)
    const float* Ws  = (const float*)d_in[2] + IN_F * SDIM;
    const float* bs  = (const float*)d_in[3] + SDIM;
    const float* Wh  = (const float*)d_in[4] + IN_F * PDIM;
    const float* bh  = (const float*)d_in[5] + PDIM;
    const float* Wo1 = (const float*)d_in[6] + IN_F * IN_F;
    const float* Wo2 = (const float*)d_in[7] + 2 * PDIM * IN_F;
    const float* bo2 = (const float*)d_in[8] + IN_F;
    const float* W1  = (const float*)d_in[9];
    const float* b1  = (const float*)d_in[10];
    const float* W2  = (const float*)d_in[11];
    const float* b2  = (const float*)d_in[12];
    const float* W3  = (const float*)d_in[13];
    const float* b3  = (const float*)d_in[14];
    float* out = (float*)d_out;

    char* ws = (char*)d_ws;
    int*   ranges = (int*)(ws + OFF_RANGES);
    float* S      = (float*)(ws + OFF_S);
    float* H      = (float*)(ws + OFF_H);
    float* PD2    = (float*)(ws + OFF_PD2);
    int*   PIX    = (int*)(ws + OFF_PIX);
    int*   KIDX   = (int*)(ws + OFF_KIDX);
    float* KW     = (float*)(ws + OFF_KW);

    k_ranges<<<dim3(NPT / 256), dim3(256), 0, stream>>>(batch, ranges);
    k_sh<<<dim3(NPT * 32 / 256), dim3(256), 0, stream>>>(x, batch, Ws, bs, Wh, bh, S, H);
    k_knn<<<dim3(NPT / 256, CH), dim3(256), 0, stream>>>((const float4*)S, batch, ranges, PD2, PIX);
    k_merge<<<dim3(NPT / 64), dim3(64), 0, stream>>>(PD2, PIX, KIDX, KW);
    k_fused<<<dim3(NPT / ROWS), dim3(256), 0, stream>>>(x, H, KIDX, KW, Wo1, Wo2, bo2,
                                                        W1, b1, W2, b2, W3, b3, out);
}